// Round 3
// 1740.659 us; speedup vs baseline: 1.0488x; 1.0488x over previous
//
#include <hip/hip_runtime.h>

#define H_ 1024
#define B_ 128
#define S_ 512
#define V_ 128
#define E_ 256

// LDS layout (bytes)
#define ZSH_OFF 0            // 67584  [8 w][16 row][132] f32 partials
#define TSH_OFF 67584        // 67584  [128 v][132] f32 tokproj slice
#define HSH_OFF 135168       // 1024   packed h slice ushort[16 row][32 hu]
#define XSH_OFF 136192       // 64     int[16] tokens
#define SMEM_TOTAL 136256

#define HXBUF 131072         // ushorts per hX buffer (256 blocks * 512)

typedef __bf16 bf16x8 __attribute__((ext_vector_type(8)));
typedef float f32x4 __attribute__((ext_vector_type(4)));
typedef unsigned long long ull;

// Coherent (device-scope, L1/L2-bypass) 16-B load; ~1 lane-request/cyc at the
// CU (validated in earlier session: step time tracks per-CU request count).
__device__ __forceinline__ uint4 cload16(const unsigned short* p) {
  uint4 r;
  asm volatile("global_load_dwordx4 %0, %1, off sc0 sc1"
               : "=v"(r) : "v"(p) : "memory");
  return r;
}
// Coherent 8-B store via compiler atomics (proven protocol).
__device__ __forceinline__ void cstore8(unsigned short* p, ull v) {
  __hip_atomic_store((ull*)p, v, __ATOMIC_RELAXED, __HIP_MEMORY_SCOPE_AGENT);
}

__device__ __forceinline__ unsigned short f2bf(float f) {
  unsigned u = __float_as_uint(f);
  u += 0x7fffu + ((u >> 16) & 1u);   // round-to-nearest-even
  return (unsigned short)(u >> 16);
}
__device__ __forceinline__ float sigf(float x) { return 1.0f / (1.0f + __expf(-x)); }
__device__ __forceinline__ float tanhfast(float x) { return 1.0f - 2.0f / (1.0f + __expf(2.0f * x)); }

// ---- tokproj[v][c] = emb[v]@Wx + b ; c = gate*1024 + j (natural layout) ----
__global__ void __launch_bounds__(256)
tokproj_kernel(const float* __restrict__ emb,
               const float* __restrict__ Wgx, const float* __restrict__ Wix,
               const float* __restrict__ Wfx, const float* __restrict__ Wox,
               const float* __restrict__ bg, const float* __restrict__ bi,
               const float* __restrict__ bf_, const float* __restrict__ bo,
               float* __restrict__ tokproj) {
  __shared__ float esh[E_];
  const int v = blockIdx.x;
  const int c = blockIdx.y * 256 + threadIdx.x;
  const int gate = c >> 10;
  const int j = c & 1023;
  const float* W = (gate == 0) ? Wgx : (gate == 1) ? Wix : (gate == 2) ? Wfx : Wox;
  const float* bias = (gate == 0) ? bg : (gate == 1) ? bi : (gate == 2) ? bf_ : bo;
  esh[threadIdx.x] = emb[v * E_ + threadIdx.x];
  __syncthreads();
  float acc = bias[j];
#pragma unroll 4
  for (int e = 0; e < E_; ++e) acc += esh[e] * W[e * H_ + j];
  tokproj[v * 4096 + c] = acc;
}

// ---- WhT[c][k] = bf16(Wh_gate[k][j]) ; c = gate*1024 + j ----
__global__ void __launch_bounds__(256)
wht_kernel(const float* __restrict__ Wgh, const float* __restrict__ Wih,
           const float* __restrict__ Wfh, const float* __restrict__ Woh,
           unsigned short* __restrict__ WhT) {
  const int c = blockIdx.x;
  const int gate = c >> 10;
  const int j = c & 1023;
  const float* W = (gate == 0) ? Wgh : (gate == 1) ? Wih : (gate == 2) ? Wfh : Woh;
  for (int k = threadIdx.x; k < H_; k += 256)
    WhT[c * H_ + k] = f2bf(W[k * H_ + j]);
}

// ---- xT[s][b] = x[b][s] ----
__global__ void __launch_bounds__(256)
xpose_kernel(const int* __restrict__ x, int* __restrict__ xT) {
  const int id = blockIdx.x * 256 + threadIdx.x;  // 65536
  const int s = id >> 7, b = id & 127;
  xT[s * 128 + b] = x[b * S_ + s];
}

// ---- persistent scan: 256 blocks x 512 thr (1 per CU) ----
// bid: rg = bid>>5 owns batch rows [rg*16,+16); cg = bid&31 owns hidden units
// [cg*32,+32)  (baseline mapping, proven).
// h slice (1 KB) is published FRAGMENT-MAJOR: 16B chunk c holds
// h[row=c&15][hu 8-chunk c>>4]. A wave's MFMA A-fragment is then a unit-stride
// 64-lane x 16B load straight from the producer slice (chunk = lane): no LDS
// staging, barriers B/D deleted.
// Wave split: wave w owns k-slice [w*128,+128) x ALL 128 gate-cols ->
// 4 producers per wave (w*4..w*4+3), 8 waves cover all 32 producers exactly
// once (4 loads/lane = same request count as baseline staging).
__global__ void __launch_bounds__(512, 1)
lstm_scan(const int* __restrict__ xT, const float* __restrict__ tokproj,
          const unsigned short* __restrict__ WhT,
          unsigned short* __restrict__ hX, float* __restrict__ hfin,
          unsigned* __restrict__ pub) {
  extern __shared__ char smem[];
  float* Zsh = (float*)(smem + ZSH_OFF);
  float* tsh = (float*)(smem + TSH_OFF);
  unsigned short* hsh = (unsigned short*)(smem + HSH_OFF);
  int* xsh = (int*)(smem + XSH_OFF);

  const int bid = blockIdx.x;
  const int rg = bid >> 5;
  const int cg = bid & 31;
  const int tid = threadIdx.x;
  const int w = tid >> 6;          // k-slice owner: k in [w*128, +128)
  const int lane = tid & 63;
  const int l15 = lane & 15;
  const int lq = lane >> 4;

  // ---- one-time: tokproj slice -> LDS (block-local col j = gate*32+hu) ----
  for (int it = tid; it < 16384; it += 512) {
    const int v = it >> 7, j = it & 127;
    tsh[v * 132 + j] = tokproj[v * 4096 + (j >> 5) * 1024 + cg * 32 + (j & 31)];
  }
  // ---- one-time: B fragments -> registers ----
  // breg[kc*8+t]: B[k=(w*4+kc)*32+lq*8 ..+8][col=t*16+l15]
  uint4 breg[32];
#pragma unroll
  for (int kc = 0; kc < 4; ++kc) {
#pragma unroll
    for (int t = 0; t < 8; ++t) {
      const int j = t * 16 + l15;
      const int c = ((j >> 5) << 10) + cg * 32 + (j & 31);
      breg[kc * 8 + t] =
          *(const uint4*)(WhT + c * 1024 + (w * 4 + kc) * 32 + lq * 8);
    }
  }

  const int row_own = tid >> 5;      // 0..15
  const int hu = tid & 31;           // 0..31
  const int brow = rg * 16 + row_own;
  const int colg = cg * 32 + hu;

  // poll binding: lane polls producer w*4 + (lane&3); the wave reconverges
  // (and issues its loads) only after ALL 4 of its producers are ready.
  const unsigned* myflag = pub + (rg * 32 + w * 4 + (lane & 3)) * 32;
  // fragment bases: producer w*4+kc's slice, this lane's 16B chunk (= lane)
  const unsigned short* abase[4];
#pragma unroll
  for (int kc = 0; kc < 4; ++kc)
    abase[kc] = hX + (rg * 32 + w * 4 + kc) * 512 + lane * 8;

  float creg = 0.f;
  // zero own h^0 slice (buffer 0) with packed coherent stores (baseline form)
  if (tid < 128) cstore8(hX + bid * 512 + tid * 4, 0ull);
  asm volatile("s_waitcnt vmcnt(0)" ::: "memory");
  __syncthreads();
  if (tid == 0)
    __hip_atomic_store(pub + bid * 32, 1u, __ATOMIC_RELAXED, __HIP_MEMORY_SCOPE_AGENT);

  for (int s = 0; s < S_; ++s) {
    int xv = 0;
    if (tid < 16) xv = xT[s * 128 + rg * 16 + tid];

    const unsigned tgt = (unsigned)(s + 1);
    while (__hip_atomic_load(myflag, __ATOMIC_RELAXED, __HIP_MEMORY_SCOPE_AGENT) < tgt)
      __builtin_amdgcn_s_sleep(1);

    const int soff = (s & 1) * HXBUF;
    uint4 a[4];
#pragma unroll
    for (int kc = 0; kc < 4; ++kc) a[kc] = cload16(abase[kc] + soff);
    asm volatile("s_waitcnt vmcnt(0)" ::: "memory");
    __builtin_amdgcn_sched_barrier(0);
    // per-component keep-alive: re-defines a[*] AFTER the waitcnt so the MFMAs
    // cannot be hoisted above it (rule #18).
#pragma unroll
    for (int kc = 0; kc < 4; ++kc) {
      asm volatile("" : "+v"(a[kc].x), "+v"(a[kc].y), "+v"(a[kc].z), "+v"(a[kc].w));
    }

    if (tid < 16) xsh[tid] = xv;

    // ---- MFMA: wave covers k [w*128,+128) x all 128 cols ----
    f32x4 acc[8];
#pragma unroll
    for (int t = 0; t < 8; ++t) acc[t] = (f32x4){0.f, 0.f, 0.f, 0.f};
#pragma unroll
    for (int kc = 0; kc < 4; ++kc) {
      const bf16x8 av = __builtin_bit_cast(bf16x8, a[kc]);
#pragma unroll
      for (int t = 0; t < 8; ++t)
        acc[t] = __builtin_amdgcn_mfma_f32_16x16x32_bf16(
            av, __builtin_bit_cast(bf16x8, breg[kc * 8 + t]), acc[t], 0, 0, 0);
    }
#pragma unroll
    for (int t = 0; t < 8; ++t) {
#pragma unroll
      for (int r_ = 0; r_ < 4; ++r_)
        Zsh[(w * 16 + lq * 4 + r_) * 132 + t * 16 + l15] = acc[t][r_];
    }
    __syncthreads();   // F

    // ---- gate pass: thread owns (row_own, hu) ----
    {
      const int xb = xsh[row_own];
      const float* tp = tsh + xb * 132;
      float z[4];
#pragma unroll
      for (int gate = 0; gate < 4; ++gate) {
        float zz = tp[gate * 32 + hu];
#pragma unroll
        for (int w8 = 0; w8 < 8; ++w8)
          zz += Zsh[(w8 * 16 + row_own) * 132 + gate * 32 + hu];
        z[gate] = zz;
      }
      const float gv = tanhfast(z[0]);
      const float iv = sigf(z[1]);
      const float fv = sigf(z[2]);
      const float ov = sigf(z[3]);
      creg = gv * iv + creg * fv;
      const float hv = tanhfast(creg) * ov;
      hsh[row_own * 32 + hu] = f2bf(hv);
      if (s == S_ - 1) hfin[brow * H_ + colg] = hv;
    }
    __syncthreads();   // H

    // ---- packed publish (wave 0): fragment-major slice + drain + flag ----
    // chunk tid <- hsh[row=tid&15][hu-chunk=tid>>4] (16B contiguous in hsh)
    if (tid < 64) {
      const ull* hp = (const ull*)hsh;
      const int si = (tid & 15) * 8 + (tid >> 4) * 2;
      unsigned short* dst = hX + ((s + 1) & 1) * HXBUF + bid * 512 + tid * 8;
      cstore8(dst, hp[si]);
      cstore8(dst + 4, hp[si + 1]);
      asm volatile("s_waitcnt vmcnt(0)" ::: "memory");
      if (tid == 0)
        __hip_atomic_store(pub + bid * 32, (unsigned)(s + 2),
                           __ATOMIC_RELAXED, __HIP_MEMORY_SCOPE_AGENT);
    }
    // no trailing barrier: barrier F of step s+1 protects Zsh/xsh; flag order
    // certifies all peers' step-s reads completed before buffer reuse.
  }
}

// ---- p = hfin @ W_ph + b_p ; out = log_softmax(p) ----
__global__ void __launch_bounds__(256)
classify_kernel(const float* __restrict__ hfin, const float* __restrict__ Wph,
                const float* __restrict__ bp, float* __restrict__ out) {
  __shared__ float red[256 * 10];
  const int b = blockIdx.x, tid = threadIdx.x;
  float acc[10];
#pragma unroll
  for (int c = 0; c < 10; ++c) acc[c] = 0.f;
  for (int k = tid; k < H_; k += 256) {
    const float hv = hfin[b * H_ + k];
    const float* w = Wph + k * 10;
#pragma unroll
    for (int c = 0; c < 10; ++c) acc[c] += hv * w[c];
  }
#pragma unroll
  for (int c = 0; c < 10; ++c) red[tid * 10 + c] = acc[c];
  __syncthreads();
  for (int off = 128; off >= 1; off >>= 1) {
    if (tid < off) {
#pragma unroll
      for (int c = 0; c < 10; ++c) red[tid * 10 + c] += red[(tid + off) * 10 + c];
    }
    __syncthreads();
  }
  if (tid == 0) {
    float p[10];
    float m = -1e30f;
#pragma unroll
    for (int c = 0; c < 10; ++c) { p[c] = red[c] + bp[c]; m = fmaxf(m, p[c]); }
    float ssum = 0.f;
#pragma unroll
    for (int c = 0; c < 10; ++c) ssum += __expf(p[c] - m);
    const float lse = m + __logf(ssum);
#pragma unroll
    for (int c = 0; c < 10; ++c) out[b * 10 + c] = p[c] - lse;
  }
}

extern "C" void kernel_launch(void* const* d_in, const int* in_sizes, int n_in,
                              void* d_out, int out_size, void* d_ws, size_t ws_size,
                              hipStream_t stream) {
  (void)in_sizes; (void)n_in; (void)out_size; (void)ws_size;
  const int* x = (const int*)d_in[0];
  const float* emb = (const float*)d_in[1];
  const float* Wgx = (const float*)d_in[2];
  const float* Wgh = (const float*)d_in[3];
  const float* bg = (const float*)d_in[4];
  const float* Wix = (const float*)d_in[5];
  const float* Wih = (const float*)d_in[6];
  const float* bi = (const float*)d_in[7];
  const float* Wfx = (const float*)d_in[8];
  const float* Wfh = (const float*)d_in[9];
  const float* bf_ = (const float*)d_in[10];
  const float* Wox = (const float*)d_in[11];
  const float* Woh = (const float*)d_in[12];
  const float* bo = (const float*)d_in[13];
  const float* Wph = (const float*)d_in[14];
  const float* bp = (const float*)d_in[15];
  float* out = (float*)d_out;

  char* ws = (char*)d_ws;
  float* tokproj = (float*)ws;                                  // 2 MB
  unsigned short* WhT = (unsigned short*)(ws + 2097152);        // 8 MB
  unsigned short* hX = (unsigned short*)(ws + 10485760);        // 512 KB (2 bufs)
  float* hfin = (float*)(ws + 11010048);                        // 512 KB
  int* xT = (int*)(ws + 11538432);                              // 256 KB
  unsigned* pub = (unsigned*)(ws + 11800576);                   // 32 KB flags

  (void)hipMemsetAsync(pub, 0, 32768, stream);
  (void)hipFuncSetAttribute(reinterpret_cast<const void*>(lstm_scan),
                            hipFuncAttributeMaxDynamicSharedMemorySize, SMEM_TOTAL);

  tokproj_kernel<<<dim3(V_, 16), dim3(256), 0, stream>>>(
      emb, Wgx, Wix, Wfx, Wox, bg, bi, bf_, bo, tokproj);
  wht_kernel<<<dim3(4096), dim3(256), 0, stream>>>(Wgh, Wih, Wfh, Woh, WhT);
  xpose_kernel<<<dim3(256), dim3(256), 0, stream>>>(x, xT);
  lstm_scan<<<dim3(256), dim3(512), SMEM_TOTAL, stream>>>(
      xT, tokproj, WhT, hX, hfin, pub);
  classify_kernel<<<dim3(128), dim3(256), 0, stream>>>(hfin, Wph, bp, out);
}

// Round 7
// 1709.066 us; speedup vs baseline: 1.0682x; 1.0185x over previous
//
#include <hip/hip_runtime.h>

#define H_ 1024
#define B_ 128
#define S_ 512
#define V_ 128
#define E_ 256

// LDS layout (bytes)
// Zsh: [8 w8][16 row][33 hu-slots][4 gates] f32  (pad 33 breaks bank aliasing)
// tsh: [128 v][33 hu-slots][4 gates] f32
#define ZSH_OFF 0            // 67584
#define TSH_OFF 67584        // 67584
#define HSH_OFF 135168       // 1024   packed h slice ushort[16 row][32 hu]
#define XSH_OFF 136192       // 64     int[16] tokens
#define SMEM_TOTAL 136256

#define HXBUF 131072         // ushorts per hX buffer (256 blocks * 512)

typedef __bf16 bf16x8 __attribute__((ext_vector_type(8)));
typedef float f32x4 __attribute__((ext_vector_type(4)));
typedef unsigned long long ull;

// Coherent (device-scope, L1/L2-bypass) 16-B load; ~1 lane-request/cyc at the
// CU (validated in earlier session: step time tracks per-CU request count).
__device__ __forceinline__ uint4 cload16(const unsigned short* p) {
  uint4 r;
  asm volatile("global_load_dwordx4 %0, %1, off sc0 sc1"
               : "=v"(r) : "v"(p) : "memory");
  return r;
}
// Coherent 8-B store via compiler atomics (proven protocol).
__device__ __forceinline__ void cstore8(unsigned short* p, ull v) {
  __hip_atomic_store((ull*)p, v, __ATOMIC_RELAXED, __HIP_MEMORY_SCOPE_AGENT);
}

__device__ __forceinline__ unsigned short f2bf(float f) {
  unsigned u = __float_as_uint(f);
  u += 0x7fffu + ((u >> 16) & 1u);   // round-to-nearest-even
  return (unsigned short)(u >> 16);
}
__device__ __forceinline__ float sigf(float x) { return 1.0f / (1.0f + __expf(-x)); }
__device__ __forceinline__ float tanhfast(float x) { return 1.0f - 2.0f / (1.0f + __expf(2.0f * x)); }

// ---- fused prep: tokproj (bid<2048) | WhT (bid<6144) | xpose (bid<6400) ----
__global__ void __launch_bounds__(256)
prep_kernel(const float* __restrict__ emb,
            const float* __restrict__ Wgx, const float* __restrict__ Wix,
            const float* __restrict__ Wfx, const float* __restrict__ Wox,
            const float* __restrict__ bg, const float* __restrict__ bi,
            const float* __restrict__ bf_, const float* __restrict__ bo,
            const float* __restrict__ Wgh, const float* __restrict__ Wih,
            const float* __restrict__ Wfh, const float* __restrict__ Woh,
            const int* __restrict__ x,
            float* __restrict__ tokproj, unsigned short* __restrict__ WhT,
            int* __restrict__ xT) {
  __shared__ float esh[E_];
  const int bid = blockIdx.x;
  if (bid < 2048) {
    // tokproj[v][c] = emb[v]@Wx + b ; c = gate*1024 + j (natural layout)
    const int v = bid >> 4;
    const int c = (bid & 15) * 256 + threadIdx.x;
    const int gate = c >> 10;
    const int j = c & 1023;
    const float* W = (gate == 0) ? Wgx : (gate == 1) ? Wix : (gate == 2) ? Wfx : Wox;
    const float* bias = (gate == 0) ? bg : (gate == 1) ? bi : (gate == 2) ? bf_ : bo;
    esh[threadIdx.x] = emb[v * E_ + threadIdx.x];
    __syncthreads();
    float acc = bias[j];
#pragma unroll 4
    for (int e = 0; e < E_; ++e) acc += esh[e] * W[e * H_ + j];
    tokproj[v * 4096 + c] = acc;
  } else if (bid < 6144) {
    // WhT[c][k] = bf16(Wh_gate[k][j]) ; c = gate*1024 + j
    const int c = bid - 2048;
    const int gate = c >> 10;
    const int j = c & 1023;
    const float* W = (gate == 0) ? Wgh : (gate == 1) ? Wih : (gate == 2) ? Wfh : Woh;
    for (int k = threadIdx.x; k < H_; k += 256)
      WhT[c * H_ + k] = f2bf(W[k * H_ + j]);
  } else {
    // xT[s][b] = x[b][s]
    const int id = (bid - 6144) * 256 + threadIdx.x;  // 65536
    const int s = id >> 7, b = id & 127;
    xT[s * 128 + b] = x[b * S_ + s];
  }
}

// ---- persistent scan: 256 blocks x 512 thr (1 per CU) ----
// bid: rg = bid>>5 owns batch rows [rg*16,+16); cg = bid&31 owns hidden units
// [cg*32,+32)  (baseline mapping, proven).
// h slice (1 KB) is published FRAGMENT-MAJOR: 16B chunk c holds
// h[row=c&15][hu 8-chunk c>>4]. A wave's MFMA A-fragment is then a unit-stride
// 64-lane x 16B load straight from the producer slice (chunk = lane): no LDS
// staging.
// Wave split: wave w owns k-slice [w*128,+128) x ALL 128 gate-cols ->
// 4 producers per wave (w*4..w*4+3), 8 waves cover all 32 producers once.
// Gate phase uses [..][hu][4-gate] LDS layouts so all reads/writes are b128
// (40 -> 9 LDS instr/thread on the barrier-F..barrier-H critical segment);
// per-gate summation order unchanged -> bit-identical results.
__global__ void __launch_bounds__(512, 1)
lstm_scan(const int* __restrict__ xT, const float* __restrict__ tokproj,
          const unsigned short* __restrict__ WhT,
          unsigned short* __restrict__ hX, float* __restrict__ hfin,
          unsigned* __restrict__ pub) {
  extern __shared__ char smem[];
  float* Zsh = (float*)(smem + ZSH_OFF);
  float* tsh = (float*)(smem + TSH_OFF);
  unsigned short* hsh = (unsigned short*)(smem + HSH_OFF);
  int* xsh = (int*)(smem + XSH_OFF);

  const int bid = blockIdx.x;
  const int rg = bid >> 5;
  const int cg = bid & 31;
  const int tid = threadIdx.x;
  const int w = tid >> 6;          // k-slice owner: k in [w*128, +128)
  const int lane = tid & 63;
  const int l15 = lane & 15;
  const int lq = lane >> 4;

  // ---- one-time: tokproj slice -> LDS as [v][hu][gate] ----
  for (int it = tid; it < 16384; it += 512) {
    const int v = it >> 7, j = it & 127;
    const int gate = j >> 5, hu = j & 31;
    tsh[(v * 33 + hu) * 4 + gate] = tokproj[v * 4096 + gate * 1024 + cg * 32 + hu];
  }
  // ---- one-time: B fragments -> registers ----
  // breg[kc*8+t]: B[k=(w*4+kc)*32+lq*8 ..+8][col=t*16+l15]
  uint4 breg[32];
#pragma unroll
  for (int kc = 0; kc < 4; ++kc) {
#pragma unroll
    for (int t = 0; t < 8; ++t) {
      const int j = t * 16 + l15;
      const int c = ((j >> 5) << 10) + cg * 32 + (j & 31);
      breg[kc * 8 + t] =
          *(const uint4*)(WhT + c * 1024 + (w * 4 + kc) * 32 + lq * 8);
    }
  }

  const int row_own = tid >> 5;      // 0..15
  const int hu = tid & 31;           // 0..31
  const int brow = rg * 16 + row_own;
  const int colg = cg * 32 + hu;

  // poll binding: lane polls producer w*4 + (lane&3); the wave reconverges
  // (and issues its loads) only after ALL 4 of its producers are ready.
  const unsigned* myflag = pub + (rg * 32 + w * 4 + (lane & 3)) * 32;
  // fragment bases: producer w*4+kc's slice, this lane's 16B chunk (= lane)
  const unsigned short* abase[4];
#pragma unroll
  for (int kc = 0; kc < 4; ++kc)
    abase[kc] = hX + (rg * 32 + w * 4 + kc) * 512 + lane * 8;

  float creg = 0.f;
  // zero own h^0 slice (buffer 0) with packed coherent stores (baseline form)
  if (tid < 128) cstore8(hX + bid * 512 + tid * 4, 0ull);
  asm volatile("s_waitcnt vmcnt(0)" ::: "memory");
  __syncthreads();
  if (tid == 0)
    __hip_atomic_store(pub + bid * 32, 1u, __ATOMIC_RELAXED, __HIP_MEMORY_SCOPE_AGENT);

  for (int s = 0; s < S_; ++s) {
    int xv = 0;
    if (tid < 16) xv = xT[s * 128 + rg * 16 + tid];

    const unsigned tgt = (unsigned)(s + 1);
    while (__hip_atomic_load(myflag, __ATOMIC_RELAXED, __HIP_MEMORY_SCOPE_AGENT) < tgt)
      __builtin_amdgcn_s_sleep(1);

    const int soff = (s & 1) * HXBUF;
    uint4 a[4];
#pragma unroll
    for (int kc = 0; kc < 4; ++kc) a[kc] = cload16(abase[kc] + soff);
    asm volatile("s_waitcnt vmcnt(0)" ::: "memory");
    __builtin_amdgcn_sched_barrier(0);
    // per-component keep-alive: re-defines a[*] AFTER the waitcnt so the MFMAs
    // cannot be hoisted above it (rule #18).
#pragma unroll
    for (int kc = 0; kc < 4; ++kc) {
      asm volatile("" : "+v"(a[kc].x), "+v"(a[kc].y), "+v"(a[kc].z), "+v"(a[kc].w));
    }

    if (tid < 16) xsh[tid] = xv;

    // ---- MFMA: wave covers k [w*128,+128) x all 128 cols ----
    f32x4 acc[8];
#pragma unroll
    for (int t = 0; t < 8; ++t) acc[t] = (f32x4){0.f, 0.f, 0.f, 0.f};
#pragma unroll
    for (int kc = 0; kc < 4; ++kc) {
      const bf16x8 av = __builtin_bit_cast(bf16x8, a[kc]);
#pragma unroll
      for (int t = 0; t < 8; ++t)
        acc[t] = __builtin_amdgcn_mfma_f32_16x16x32_bf16(
            av, __builtin_bit_cast(bf16x8, breg[kc * 8 + t]), acc[t], 0, 0, 0);
    }
    // epilogue: pack per-row gate quads -> 2 b128 writes per r_ (was 8 b32)
    // tile t=2g covers hu=l15, t=2g+1 covers hu=l15+16 (gate g)
#pragma unroll
    for (int r_ = 0; r_ < 4; ++r_) {
      const int row = w * 16 + lq * 4 + r_;
      f32x4 lo = {acc[0][r_], acc[2][r_], acc[4][r_], acc[6][r_]};
      f32x4 hi = {acc[1][r_], acc[3][r_], acc[5][r_], acc[7][r_]};
      *(f32x4*)(Zsh + (row * 33 + l15) * 4) = lo;
      *(f32x4*)(Zsh + (row * 33 + l15 + 16) * 4) = hi;
    }
    __syncthreads();   // F

    // ---- gate pass: thread owns (row_own, hu); all-b128 LDS ----
    {
      const int xb = xsh[row_own];
      f32x4 z4 = *(const f32x4*)(tsh + (xb * 33 + hu) * 4);
#pragma unroll
      for (int w8 = 0; w8 < 8; ++w8)
        z4 += *(const f32x4*)(Zsh + ((w8 * 16 + row_own) * 33 + hu) * 4);
      const float gv = tanhfast(z4[0]);
      const float iv = sigf(z4[1]);
      const float fv = sigf(z4[2]);
      const float ov = sigf(z4[3]);
      creg = gv * iv + creg * fv;
      const float hv = tanhfast(creg) * ov;
      hsh[row_own * 32 + hu] = f2bf(hv);
      if (s == S_ - 1) hfin[brow * H_ + colg] = hv;
    }
    __syncthreads();   // H

    // ---- packed publish (wave 0): fragment-major slice + drain + flag ----
    // chunk tid <- hsh[row=tid&15][hu-chunk=tid>>4] (16B contiguous in hsh)
    if (tid < 64) {
      const ull* hp = (const ull*)hsh;
      const int si = (tid & 15) * 8 + (tid >> 4) * 2;
      unsigned short* dst = hX + ((s + 1) & 1) * HXBUF + bid * 512 + tid * 8;
      cstore8(dst, hp[si]);
      cstore8(dst + 4, hp[si + 1]);
      asm volatile("s_waitcnt vmcnt(0)" ::: "memory");
      if (tid == 0)
        __hip_atomic_store(pub + bid * 32, (unsigned)(s + 2),
                           __ATOMIC_RELAXED, __HIP_MEMORY_SCOPE_AGENT);
    }
    // no trailing barrier: barrier F of step s+1 protects Zsh/xsh; flag order
    // certifies all peers' step-s reads completed before buffer reuse.
  }
}

// ---- p = hfin @ W_ph + b_p ; out = log_softmax(p) ----
__global__ void __launch_bounds__(256)
classify_kernel(const float* __restrict__ hfin, const float* __restrict__ Wph,
                const float* __restrict__ bp, float* __restrict__ out) {
  __shared__ float red[256 * 10];
  const int b = blockIdx.x, tid = threadIdx.x;
  float acc[10];
#pragma unroll
  for (int c = 0; c < 10; ++c) acc[c] = 0.f;
  for (int k = tid; k < H_; k += 256) {
    const float hv = hfin[b * H_ + k];
    const float* w = Wph + k * 10;
#pragma unroll
    for (int c = 0; c < 10; ++c) acc[c] += hv * w[c];
  }
#pragma unroll
  for (int c = 0; c < 10; ++c) red[tid * 10 + c] = acc[c];
  __syncthreads();
  for (int off = 128; off >= 1; off >>= 1) {
    if (tid < off) {
#pragma unroll
      for (int c = 0; c < 10; ++c) red[tid * 10 + c] += red[(tid + off) * 10 + c];
    }
    __syncthreads();
  }
  if (tid == 0) {
    float p[10];
    float m = -1e30f;
#pragma unroll
    for (int c = 0; c < 10; ++c) { p[c] = red[c] + bp[c]; m = fmaxf(m, p[c]); }
    float ssum = 0.f;
#pragma unroll
    for (int c = 0; c < 10; ++c) ssum += __expf(p[c] - m);
    const float lse = m + __logf(ssum);
#pragma unroll
    for (int c = 0; c < 10; ++c) out[b * 10 + c] = p[c] - lse;
  }
}

extern "C" void kernel_launch(void* const* d_in, const int* in_sizes, int n_in,
                              void* d_out, int out_size, void* d_ws, size_t ws_size,
                              hipStream_t stream) {
  (void)in_sizes; (void)n_in; (void)out_size; (void)ws_size;
  const int* x = (const int*)d_in[0];
  const float* emb = (const float*)d_in[1];
  const float* Wgx = (const float*)d_in[2];
  const float* Wgh = (const float*)d_in[3];
  const float* bg = (const float*)d_in[4];
  const float* Wix = (const float*)d_in[5];
  const float* Wih = (const float*)d_in[6];
  const float* bi = (const float*)d_in[7];
  const float* Wfx = (const float*)d_in[8];
  const float* Wfh = (const float*)d_in[9];
  const float* bf_ = (const float*)d_in[10];
  const float* Wox = (const float*)d_in[11];
  const float* Woh = (const float*)d_in[12];
  const float* bo = (const float*)d_in[13];
  const float* Wph = (const float*)d_in[14];
  const float* bp = (const float*)d_in[15];
  float* out = (float*)d_out;

  char* ws = (char*)d_ws;
  float* tokproj = (float*)ws;                                  // 2 MB
  unsigned short* WhT = (unsigned short*)(ws + 2097152);        // 8 MB
  unsigned short* hX = (unsigned short*)(ws + 10485760);        // 512 KB (2 bufs)
  float* hfin = (float*)(ws + 11010048);                        // 512 KB
  int* xT = (int*)(ws + 11538432);                              // 256 KB
  unsigned* pub = (unsigned*)(ws + 11800576);                   // 32 KB flags

  (void)hipMemsetAsync(pub, 0, 32768, stream);
  (void)hipFuncSetAttribute(reinterpret_cast<const void*>(lstm_scan),
                            hipFuncAttributeMaxDynamicSharedMemorySize, SMEM_TOTAL);

  prep_kernel<<<dim3(6400), dim3(256), 0, stream>>>(
      emb, Wgx, Wix, Wfx, Wox, bg, bi, bf_, bo,
      Wgh, Wih, Wfh, Woh, x, tokproj, WhT, xT);
  lstm_scan<<<dim3(256), dim3(512), SMEM_TOTAL, stream>>>(
      xT, tokproj, WhT, hX, hfin, pub);
  classify_kernel<<<dim3(128), dim3(256), 0, stream>>>(hfin, Wph, bp, out);
}